// Round 19
// baseline (156.480 us; speedup 1.0000x reference)
//
#include <hip/hip_runtime.h>

#define HID 128
#define EMB 256
#define NL 3
#define NEDGE 640000
#define NNODE 40000
#define BM 128                   // rows per mlp block
#define NPAD 40064               // NNODE padded to BM multiple (313 blocks)
#define CAP 64                   // fixed per-node bucket capacity (Poisson(16): P(>64)~2e-18)

typedef unsigned short u16;
typedef __attribute__((ext_vector_type(8))) __bf16 bf16x8;
typedef __attribute__((ext_vector_type(4))) float f32x4;

union Frag {
  uint4 q;
  bf16x8 v;
  u16 u[8];
};

union Pack4 {
  uint2 q;
  u16 u[4];
};

__device__ inline u16 f2b(float f) {  // round-to-nearest (ties up), 2 insts
  return (u16)((__float_as_uint(f) + 0x8000u) >> 16);
}
__device__ inline float b2f(u16 h) { return __uint_as_float(((unsigned)h) << 16); }

// swizzled index into a [BM][EMB] bf16 LDS tile (row stride 512 B).
// XOR byte-bits 4..6 with row&7; 8B/16B-aligned groups stay contiguous.
__device__ inline int sidx(int row, int k) {
  return row * EMB + ((((k) << 1) ^ ((row & 7) << 4)) >> 1);
}

// -------- weight prep: COALESCED reads, scattered wave-tiled writes ----------
__global__ void prep_weights(const float* __restrict__ Wup, const float* __restrict__ Wlins,
                             u16* __restrict__ wtup, u16* __restrict__ wtlin,
                             int* __restrict__ cnt) {
  int t = blockIdx.x * blockDim.x + threadIdx.x;
  if (t < NNODE) cnt[t] = 0;
  if (t < EMB * HID) {
    int k = t >> 8, col = t & 255;               // Wup[k][col], coalesced in col
    int wg = col >> 6, ct = (col >> 4) & 3, j16 = col & 15;
    int ks = k >> 5, kr = k & 31, jg = kr >> 3, m = kr & 7;
    int j = jg * 16 + j16;
    wtup[(((wg * 4 + ks) * 4 + ct) << 9) + j * 8 + m] = f2b(Wup[t]);
  }
  if (t < NL * EMB * EMB) {
    int l = t >> 16, r = t & 65535;
    int k = r >> 8, col = r & 255;               // Wlins[l][k][col], coalesced in col
    int wg = col >> 6, ct = (col >> 4) & 3, j16 = col & 15;
    int ks = k >> 5, kr = k & 31, jg = kr >> 3, m = kr & 7;
    int j = jg * 16 + j16;
    wtlin[l * EMB * EMB + (((wg * 8 + ks) * 4 + ct) << 9) + j * 8 + m] = f2b(Wlins[t]);
  }
}

// ------ one-pass bucket fill: p = atomicAdd(cnt) gives both count and slot ------
__global__ void fill_kernel(const int* __restrict__ idx, int* __restrict__ cnt,
                            int* __restrict__ bucket) {
  int t = blockIdx.x * blockDim.x + threadIdx.x;  // < NEDGE/4
  int4 id = reinterpret_cast<const int4*>(idx)[t];
  int e0 = t * 4;
  int p;
  p = atomicAdd(&cnt[id.x], 1); if (p < CAP) bucket[id.x * CAP + p] = e0;
  p = atomicAdd(&cnt[id.y], 1); if (p < CAP) bucket[id.y * CAP + p] = e0 + 1;
  p = atomicAdd(&cnt[id.z], 1); if (p < CAP) bucket[id.z * CAP + p] = e0 + 2;
  p = atomicAdd(&cnt[id.w], 1); if (p < CAP) bucket[id.w * CAP + p] = e0 + 3;
}

// ------- gather-sum: vb[node] = bf16(sum of its e2 rows); 8 lanes/node, ILP 4 ----
__global__ __launch_bounds__(256) void gather_kernel(const float* __restrict__ e2,
                                                     const int* __restrict__ bucket,
                                                     const int* __restrict__ cnt,
                                                     u16* __restrict__ vb) {
  int node = blockIdx.x * 32 + (threadIdx.x >> 3);
  int lane = threadIdx.x & 7;  // floats [lane*16, lane*16+16)
  int n = min(cnt[node], CAP);
  const int* bk = bucket + node * CAP;
  f32x4 a0 = (f32x4)(0.f), a1 = (f32x4)(0.f), a2 = (f32x4)(0.f), a3 = (f32x4)(0.f);
  int e = (n > 0) ? bk[0] : 0;
  for (int j = 0; j < n; ++j) {
    int en = (j + 1 < n) ? bk[j + 1] : 0;  // prefetch next edge id
    const f32x4* r = reinterpret_cast<const f32x4*>(e2 + (size_t)e * HID + lane * 16);
    a0 += r[0];
    a1 += r[1];
    a2 += r[2];
    a3 += r[3];
    e = en;
  }
  Frag f0, f1;
  f0.u[0] = f2b(a0.x); f0.u[1] = f2b(a0.y); f0.u[2] = f2b(a0.z); f0.u[3] = f2b(a0.w);
  f0.u[4] = f2b(a1.x); f0.u[5] = f2b(a1.y); f0.u[6] = f2b(a1.z); f0.u[7] = f2b(a1.w);
  f1.u[0] = f2b(a2.x); f1.u[1] = f2b(a2.y); f1.u[2] = f2b(a2.z); f1.u[3] = f2b(a2.w);
  f1.u[4] = f2b(a3.x); f1.u[5] = f2b(a3.y); f1.u[6] = f2b(a3.z); f1.u[7] = f2b(a3.w);
  uint4* dst = reinterpret_cast<uint4*>(vb + (size_t)node * HID + lane * 16);
  dst[0] = f0.q;
  dst[1] = f1.q;
}

// ---- fused MLP: 128 rows/block, 4 waves, 64KB LDS, swapped-operand MFMA ----
// 8 rt streams/wave (deep ds_read->MFMA pipeline), barriers amortized over 2x rows,
// weight traffic halved (313 blocks). acc 128 + frags ~170 VGPR < 256 cap at (256,2).
__global__ __launch_bounds__(256, 2) void mlp_kernel(
    const u16* __restrict__ vb,       // [NPAD][HID] bf16 (gather output; rows>=NNODE garbage)
    const u16* __restrict__ wtup,     // wave-tiled W_up^T
    const float* __restrict__ bup,    // [EMB]
    const u16* __restrict__ wtlin,    // wave-tiled W_lin^T per layer
    const float* __restrict__ blin,   // [NL][EMB]
    const float* __restrict__ wout,   // [EMB] f32
    float* __restrict__ out) {        // [N]
  __shared__ __attribute__((aligned(16))) u16 act[BM * EMB];  // 64 KB

  const int tid = threadIdx.x;
  const int wv = tid >> 6;     // wave 0..3 owns cols wv*64 .. wv*64+63
  const int lane = tid & 63;
  const int l16 = lane & 15;
  const int kg = lane >> 4;    // k-group 0..3
  const int row0 = blockIdx.x * BM;

  f32x4 acc[8][4];

  // ---------- layer 1: vb[128x128] @ W_up + b_up (A direct from global bf16) ----
#pragma unroll
  for (int ct = 0; ct < 4; ++ct) {
    int colb = wv * 64 + ct * 16 + kg * 4;
    float4 bb = *reinterpret_cast<const float4*>(bup + colb);
    f32x4 bv = {bb.x, bb.y, bb.z, bb.w};
#pragma unroll
    for (int rt = 0; rt < 8; ++rt)
      acc[rt][ct] = bv;
  }

#pragma unroll
  for (int ks = 0; ks < HID / 32; ++ks) {
    Frag bf[4];
#pragma unroll
    for (int ct = 0; ct < 4; ++ct)
      bf[ct].q = *reinterpret_cast<const uint4*>(wtup + (((wv * 4 + ks) * 4 + ct) << 9) + lane * 8);
#pragma unroll
    for (int rt = 0; rt < 8; ++rt) {
      Frag af;
      af.q = *reinterpret_cast<const uint4*>(vb + (size_t)(row0 + rt * 16 + l16) * HID + ks * 32 + kg * 8);
#pragma unroll
      for (int ct = 0; ct < 4; ++ct)
        acc[rt][ct] = __builtin_amdgcn_mfma_f32_16x16x32_bf16(bf[ct].v, af.v, acc[rt][ct], 0, 0, 0);
    }
  }
  // epilogue: pack 4 cols, ds_write_b64 (bias already in acc)
#pragma unroll
  for (int ct = 0; ct < 4; ++ct) {
    int colb = wv * 64 + ct * 16 + kg * 4;
#pragma unroll
    for (int rt = 0; rt < 8; ++rt) {
      Pack4 p;
      p.u[0] = f2b(acc[rt][ct][0]);
      p.u[1] = f2b(acc[rt][ct][1]);
      p.u[2] = f2b(acc[rt][ct][2]);
      p.u[3] = f2b(acc[rt][ct][3]);
      *reinterpret_cast<uint2*>(&act[sidx(rt * 16 + l16, colb)]) = p.q;
    }
  }
  __syncthreads();

  // ---------- layers 2..4: silu(h @ W + b), single-buffer (2 barriers/layer) ----
  for (int l = 0; l < NL; ++l) {
    const u16* wt = wtlin + l * EMB * EMB;
    const float* bl = blin + l * EMB;
#pragma unroll
    for (int ct = 0; ct < 4; ++ct) {
      int colb = wv * 64 + ct * 16 + kg * 4;
      float4 bb = *reinterpret_cast<const float4*>(bl + colb);
      f32x4 bv = {bb.x, bb.y, bb.z, bb.w};
#pragma unroll
      for (int rt = 0; rt < 8; ++rt)
        acc[rt][ct] = bv;
    }

#pragma unroll
    for (int ks = 0; ks < EMB / 32; ++ks) {
      Frag bf[4];
#pragma unroll
      for (int ct = 0; ct < 4; ++ct)
        bf[ct].q = *reinterpret_cast<const uint4*>(wt + (((wv * 8 + ks) * 4 + ct) << 9) + lane * 8);
#pragma unroll
      for (int rt = 0; rt < 8; ++rt) {
        Frag af;
        af.q = *reinterpret_cast<const uint4*>(&act[sidx(rt * 16 + l16, ks * 32 + kg * 8)]);
#pragma unroll
        for (int ct = 0; ct < 4; ++ct)
          acc[rt][ct] = __builtin_amdgcn_mfma_f32_16x16x32_bf16(bf[ct].v, af.v, acc[rt][ct], 0, 0, 0);
      }
    }
    __syncthreads();  // all reads of act done before overwrite
    // epilogue: silu + pack + b64 write (bias already in acc)
#pragma unroll
    for (int ct = 0; ct < 4; ++ct) {
      int colb = wv * 64 + ct * 16 + kg * 4;
#pragma unroll
      for (int rt = 0; rt < 8; ++rt) {
        Pack4 p;
#pragma unroll
        for (int i = 0; i < 4; ++i) {
          float x = acc[rt][ct][i];
          float s = x * __builtin_amdgcn_rcpf(1.f + __expf(-x));
          p.u[i] = f2b(s);
        }
        *reinterpret_cast<uint2*>(&act[sidx(rt * 16 + l16, colb)]) = p.q;
      }
    }
    __syncthreads();
  }

  // ---------- final projection: out = h @ W_out (K=256, N=1), b128 reads ----
#pragma unroll
  for (int half = 0; half < 2; ++half) {
    int r = half * 64 + (tid >> 2);
    int part = tid & 3;
    int k0 = part * 64;
    float s = 0.f;
#pragma unroll
    for (int kb = 0; kb < 8; ++kb) {
      Frag f;
      f.q = *reinterpret_cast<const uint4*>(&act[sidx(r, k0 + kb * 8)]);
#pragma unroll
      for (int j = 0; j < 8; ++j)
        s += b2f(f.u[j]) * wout[k0 + kb * 8 + j];
    }
    s += __shfl_xor(s, 1);
    s += __shfl_xor(s, 2);
    if (part == 0 && row0 + r < NNODE) out[row0 + r] = s;
  }
}

extern "C" void kernel_launch(void* const* d_in, const int* in_sizes, int n_in,
                              void* d_out, int out_size, void* d_ws, size_t ws_size,
                              hipStream_t stream) {
  const float* e2 = (const float*)d_in[1];
  const int* idx = (const int*)d_in[2];
  const float* Wup = (const float*)d_in[4];
  const float* bup = (const float*)d_in[5];
  const float* Wlins = (const float*)d_in[6];
  const float* blin = (const float*)d_in[7];
  const float* Wout = (const float*)d_in[8];
  float* out = (float*)d_out;

  char* ws = (char*)d_ws;
  size_t off_b = 0;
  u16* vb = (u16*)(ws + off_b);      off_b += (size_t)NPAD * HID * sizeof(u16);    // 10.26 MB
  u16* wtup = (u16*)(ws + off_b);    off_b += (size_t)EMB * HID * sizeof(u16);
  u16* wtlin = (u16*)(ws + off_b);   off_b += (size_t)NL * EMB * EMB * sizeof(u16);
  int* cnt = (int*)(ws + off_b);     off_b += (size_t)NNODE * sizeof(int);
  int* bucket = (int*)(ws + off_b);  off_b += (size_t)NNODE * CAP * sizeof(int);   // 10.24 MB

  prep_weights<<<(NL * EMB * EMB + 255) / 256, 256, 0, stream>>>(Wup, Wlins, wtup, wtlin, cnt);
  fill_kernel<<<NEDGE / 4 / 256, 256, 0, stream>>>(idx, cnt, bucket);
  gather_kernel<<<NNODE / 32, 256, 0, stream>>>(e2, bucket, cnt, vb);
  mlp_kernel<<<NPAD / BM, 256, 0, stream>>>(vb, wtup, bup, wtlin, blin, Wout, out);
}

// Round 20
// 143.416 us; speedup vs baseline: 1.0911x; 1.0911x over previous
//
#include <hip/hip_runtime.h>

#define HID 128
#define EMB 256
#define NL 3
#define NEDGE 640000
#define NNODE 40000
#define CAP 64                   // fixed per-node bucket capacity (Poisson(16): P(>64)~2e-18)

typedef unsigned short u16;
typedef __attribute__((ext_vector_type(8))) __bf16 bf16x8;
typedef __attribute__((ext_vector_type(4))) float f32x4;

union Frag {
  uint4 q;
  bf16x8 v;
  u16 u[8];
};

union Pack4 {
  uint2 q;
  u16 u[4];
};

__device__ inline u16 f2b(float f) {  // round-to-nearest (ties up), 2 insts
  return (u16)((__float_as_uint(f) + 0x8000u) >> 16);
}
__device__ inline float b2f(u16 h) { return __uint_as_float(((unsigned)h) << 16); }

// swizzled index into a [64][EMB] bf16 LDS tile (row stride 512 B).
// XOR byte-bits 4..6 with row&7; 8B/16B-aligned groups stay contiguous.
__device__ inline int sidx(int row, int k) {
  return row * EMB + ((((k) << 1) ^ ((row & 7) << 4)) >> 1);
}

// -------- weight prep: COALESCED reads, scattered wave-tiled writes ----------
// Thread t reads W[t] (contiguous) and computes the wave-tiled destination:
//   tile content: lane j (j16=j&15, jg=j>>4) holds w[col=wg*64+ct*16+j16][k=ks*32+jg*8+m]
//   wtup  offset = (((wg*4+ks)*4+ct)<<9) + j*8 + m    (EMB*HID  = 2^15)
//   wtlin offset = (((wg*8+ks)*4+ct)<<9) + j*8 + m    (EMB*EMB = 2^16 per layer)
__global__ void prep_weights(const float* __restrict__ Wup, const float* __restrict__ Wlins,
                             u16* __restrict__ wtup, u16* __restrict__ wtlin,
                             int* __restrict__ cnt) {
  int t = blockIdx.x * blockDim.x + threadIdx.x;
  if (t < NNODE) cnt[t] = 0;
  if (t < EMB * HID) {
    int k = t >> 8, col = t & 255;               // Wup[k][col], coalesced in col
    int wg = col >> 6, ct = (col >> 4) & 3, j16 = col & 15;
    int ks = k >> 5, kr = k & 31, jg = kr >> 3, m = kr & 7;
    int j = jg * 16 + j16;
    wtup[(((wg * 4 + ks) * 4 + ct) << 9) + j * 8 + m] = f2b(Wup[t]);
  }
  if (t < NL * EMB * EMB) {
    int l = t >> 16, r = t & 65535;
    int k = r >> 8, col = r & 255;               // Wlins[l][k][col], coalesced in col
    int wg = col >> 6, ct = (col >> 4) & 3, j16 = col & 15;
    int ks = k >> 5, kr = k & 31, jg = kr >> 3, m = kr & 7;
    int j = jg * 16 + j16;
    wtlin[l * EMB * EMB + (((wg * 8 + ks) * 4 + ct) << 9) + j * 8 + m] = f2b(Wlins[t]);
  }
}

// ------ one-pass bucket fill: p = atomicAdd(cnt) gives both count and slot ------
__global__ void fill_kernel(const int* __restrict__ idx, int* __restrict__ cnt,
                            int* __restrict__ bucket) {
  int t = blockIdx.x * blockDim.x + threadIdx.x;  // < NEDGE/4
  int4 id = reinterpret_cast<const int4*>(idx)[t];
  int e0 = t * 4;
  int p;
  p = atomicAdd(&cnt[id.x], 1); if (p < CAP) bucket[id.x * CAP + p] = e0;
  p = atomicAdd(&cnt[id.y], 1); if (p < CAP) bucket[id.y * CAP + p] = e0 + 1;
  p = atomicAdd(&cnt[id.z], 1); if (p < CAP) bucket[id.z * CAP + p] = e0 + 2;
  p = atomicAdd(&cnt[id.w], 1); if (p < CAP) bucket[id.w * CAP + p] = e0 + 3;
}

// ------- gather-sum: vb[node] = bf16(sum of its e2 rows); 8 lanes/node, ILP 4 ----
__global__ __launch_bounds__(256) void gather_kernel(const float* __restrict__ e2,
                                                     const int* __restrict__ bucket,
                                                     const int* __restrict__ cnt,
                                                     u16* __restrict__ vb) {
  int node = blockIdx.x * 32 + (threadIdx.x >> 3);
  int lane = threadIdx.x & 7;  // floats [lane*16, lane*16+16)
  int n = min(cnt[node], CAP);
  const int* bk = bucket + node * CAP;
  f32x4 a0 = (f32x4)(0.f), a1 = (f32x4)(0.f), a2 = (f32x4)(0.f), a3 = (f32x4)(0.f);
  int e = (n > 0) ? bk[0] : 0;
  for (int j = 0; j < n; ++j) {
    int en = (j + 1 < n) ? bk[j + 1] : 0;  // prefetch next edge id
    const f32x4* r = reinterpret_cast<const f32x4*>(e2 + (size_t)e * HID + lane * 16);
    a0 += r[0];
    a1 += r[1];
    a2 += r[2];
    a3 += r[3];
    e = en;
  }
  Frag f0, f1;
  f0.u[0] = f2b(a0.x); f0.u[1] = f2b(a0.y); f0.u[2] = f2b(a0.z); f0.u[3] = f2b(a0.w);
  f0.u[4] = f2b(a1.x); f0.u[5] = f2b(a1.y); f0.u[6] = f2b(a1.z); f0.u[7] = f2b(a1.w);
  f1.u[0] = f2b(a2.x); f1.u[1] = f2b(a2.y); f1.u[2] = f2b(a2.z); f1.u[3] = f2b(a2.w);
  f1.u[4] = f2b(a3.x); f1.u[5] = f2b(a3.y); f1.u[6] = f2b(a3.z); f1.u[7] = f2b(a3.w);
  uint4* dst = reinterpret_cast<uint4*>(vb + (size_t)node * HID + lane * 16);
  dst[0] = f0.q;
  dst[1] = f1.q;
}

// ---- fused MLP: 64 rows/block, 4 waves, single 32KB LDS, swapped-operand MFMA ----
// Weight loads hit the wave-tiled layout: one contiguous 1KB segment per bf-load.
__global__ __launch_bounds__(256, 4) void mlp_kernel(
    const u16* __restrict__ vb,       // [N][HID] bf16 (gather output)
    const u16* __restrict__ wtup,     // wave-tiled W_up^T
    const float* __restrict__ bup,    // [EMB]
    const u16* __restrict__ wtlin,    // wave-tiled W_lin^T per layer
    const float* __restrict__ blin,   // [NL][EMB]
    const float* __restrict__ wout,   // [EMB] f32
    float* __restrict__ out) {        // [N]
  __shared__ __attribute__((aligned(16))) u16 act[64 * EMB];  // 32 KB

  const int tid = threadIdx.x;
  const int wv = tid >> 6;     // wave 0..3 owns cols wv*64 .. wv*64+63
  const int lane = tid & 63;
  const int l16 = lane & 15;
  const int kg = lane >> 4;    // k-group 0..3
  const int row0 = blockIdx.x * 64;

  f32x4 acc[4][4];

  // ---------- layer 1: vb[64x128] @ W_up + b_up (A direct from global bf16) ----
#pragma unroll
  for (int ct = 0; ct < 4; ++ct) {
    int colb = wv * 64 + ct * 16 + kg * 4;
    float4 bb = *reinterpret_cast<const float4*>(bup + colb);
    f32x4 bv = {bb.x, bb.y, bb.z, bb.w};
#pragma unroll
    for (int rt = 0; rt < 4; ++rt)
      acc[rt][ct] = bv;
  }

#pragma unroll
  for (int ks = 0; ks < HID / 32; ++ks) {
    Frag bf[4];
#pragma unroll
    for (int ct = 0; ct < 4; ++ct)
      bf[ct].q = *reinterpret_cast<const uint4*>(wtup + (((wv * 4 + ks) * 4 + ct) << 9) + lane * 8);
#pragma unroll
    for (int rt = 0; rt < 4; ++rt) {
      Frag af;
      af.q = *reinterpret_cast<const uint4*>(vb + (size_t)(row0 + rt * 16 + l16) * HID + ks * 32 + kg * 8);
#pragma unroll
      for (int ct = 0; ct < 4; ++ct)
        acc[rt][ct] = __builtin_amdgcn_mfma_f32_16x16x32_bf16(bf[ct].v, af.v, acc[rt][ct], 0, 0, 0);
    }
  }
  // epilogue: pack 4 cols, ds_write_b64 (bias already in acc)
#pragma unroll
  for (int ct = 0; ct < 4; ++ct) {
    int colb = wv * 64 + ct * 16 + kg * 4;
#pragma unroll
    for (int rt = 0; rt < 4; ++rt) {
      Pack4 p;
      p.u[0] = f2b(acc[rt][ct][0]);
      p.u[1] = f2b(acc[rt][ct][1]);
      p.u[2] = f2b(acc[rt][ct][2]);
      p.u[3] = f2b(acc[rt][ct][3]);
      *reinterpret_cast<uint2*>(&act[sidx(rt * 16 + l16, colb)]) = p.q;
    }
  }
  __syncthreads();

  // ---------- layers 2..4: silu(h @ W + b), single-buffer (2 barriers/layer) ----
  for (int l = 0; l < NL; ++l) {
    const u16* wt = wtlin + l * EMB * EMB;
    const float* bl = blin + l * EMB;
#pragma unroll
    for (int ct = 0; ct < 4; ++ct) {
      int colb = wv * 64 + ct * 16 + kg * 4;
      float4 bb = *reinterpret_cast<const float4*>(bl + colb);
      f32x4 bv = {bb.x, bb.y, bb.z, bb.w};
#pragma unroll
      for (int rt = 0; rt < 4; ++rt)
        acc[rt][ct] = bv;
    }

#pragma unroll
    for (int ks = 0; ks < EMB / 32; ++ks) {
      Frag bf[4];
#pragma unroll
      for (int ct = 0; ct < 4; ++ct)
        bf[ct].q = *reinterpret_cast<const uint4*>(wt + (((wv * 8 + ks) * 4 + ct) << 9) + lane * 8);
#pragma unroll
      for (int rt = 0; rt < 4; ++rt) {
        Frag af;
        af.q = *reinterpret_cast<const uint4*>(&act[sidx(rt * 16 + l16, ks * 32 + kg * 8)]);
#pragma unroll
        for (int ct = 0; ct < 4; ++ct)
          acc[rt][ct] = __builtin_amdgcn_mfma_f32_16x16x32_bf16(bf[ct].v, af.v, acc[rt][ct], 0, 0, 0);
      }
    }
    __syncthreads();  // all reads of act done before overwrite
    // epilogue: silu + pack + b64 write (bias already in acc)
#pragma unroll
    for (int ct = 0; ct < 4; ++ct) {
      int colb = wv * 64 + ct * 16 + kg * 4;
#pragma unroll
      for (int rt = 0; rt < 4; ++rt) {
        Pack4 p;
#pragma unroll
        for (int i = 0; i < 4; ++i) {
          float x = acc[rt][ct][i];
          float s = x * __builtin_amdgcn_rcpf(1.f + __expf(-x));
          p.u[i] = f2b(s);
        }
        *reinterpret_cast<uint2*>(&act[sidx(rt * 16 + l16, colb)]) = p.q;
      }
    }
    __syncthreads();
  }

  // ---------- final projection: out = h @ W_out (K=256, N=1), b128 reads ----
  int r = tid >> 2;
  int part = tid & 3;
  int k0 = part * 64;
  float s = 0.f;
#pragma unroll
  for (int kb = 0; kb < 8; ++kb) {
    Frag f;
    f.q = *reinterpret_cast<const uint4*>(&act[sidx(r, k0 + kb * 8)]);
#pragma unroll
    for (int j = 0; j < 8; ++j)
      s += b2f(f.u[j]) * wout[k0 + kb * 8 + j];
  }
  s += __shfl_xor(s, 1);
  s += __shfl_xor(s, 2);
  if (part == 0) out[row0 + r] = s;
}

extern "C" void kernel_launch(void* const* d_in, const int* in_sizes, int n_in,
                              void* d_out, int out_size, void* d_ws, size_t ws_size,
                              hipStream_t stream) {
  const float* e2 = (const float*)d_in[1];
  const int* idx = (const int*)d_in[2];
  const float* Wup = (const float*)d_in[4];
  const float* bup = (const float*)d_in[5];
  const float* Wlins = (const float*)d_in[6];
  const float* blin = (const float*)d_in[7];
  const float* Wout = (const float*)d_in[8];
  float* out = (float*)d_out;

  char* ws = (char*)d_ws;
  size_t off_b = 0;
  u16* vb = (u16*)(ws + off_b);      off_b += (size_t)NNODE * HID * sizeof(u16);   // 10.24 MB
  u16* wtup = (u16*)(ws + off_b);    off_b += (size_t)EMB * HID * sizeof(u16);
  u16* wtlin = (u16*)(ws + off_b);   off_b += (size_t)NL * EMB * EMB * sizeof(u16);
  int* cnt = (int*)(ws + off_b);     off_b += (size_t)NNODE * sizeof(int);
  int* bucket = (int*)(ws + off_b);  off_b += (size_t)NNODE * CAP * sizeof(int);   // 10.24 MB

  prep_weights<<<(NL * EMB * EMB + 255) / 256, 256, 0, stream>>>(Wup, Wlins, wtup, wtlin, cnt);
  fill_kernel<<<NEDGE / 4 / 256, 256, 0, stream>>>(idx, cnt, bucket);
  gather_kernel<<<NNODE / 32, 256, 0, stream>>>(e2, bucket, cnt, vb);
  mlp_kernel<<<NNODE / 64, 256, 0, stream>>>(vb, wtup, bup, wtlin, blin, Wout, out);
}